// Round 9
// baseline (140.174 us; speedup 1.0000x reference)
//
#include <hip/hip_runtime.h>
#include <hip/hip_bf16.h>

typedef __hip_bfloat16 bf16;
typedef __attribute__((ext_vector_type(8))) short short8;   // 8 bf16 = 4 VGPRs
typedef __attribute__((ext_vector_type(4))) short short4v;  // 4 bf16 = 2 VGPRs
typedef __attribute__((ext_vector_type(4))) float f32x4;    // MFMA C/D frag

__device__ __forceinline__ short8 ld8(const void* p) { return *(const short8*)p; }
__device__ __forceinline__ short4v ld4(const void* p) { return *(const short4v*)p; }

// async global->LDS, 16B per lane: LDS dest = (wave-uniform) base + lane*16
__device__ __forceinline__ void async_cp16(bf16* lds, const bf16* g) {
    __builtin_amdgcn_global_load_lds(
        (const __attribute__((address_space(1))) unsigned int*)g,
        (__attribute__((address_space(3))) unsigned int*)lds, 16, 0, 0);
}

struct bf4 { bf16 a, b, c, d; };

// ---------------------------------------------------------------------------
__global__ void cast_kernel(const float* __restrict__ s0, bf16* __restrict__ d0, int n0_,
                            const float* __restrict__ s1, bf16* __restrict__ d1, int n1_,
                            const float* __restrict__ s2, bf16* __restrict__ d2, int n2_,
                            const float* __restrict__ s3, bf16* __restrict__ d3, int n3_,
                            const float* __restrict__ s4, bf16* __restrict__ d4, int n4_) {
    const float* srcs[5] = {s0, s1, s2, s3, s4};
    bf16* dsts[5] = {d0, d1, d2, d3, d4};
    int ns[5] = {n0_, n1_, n2_, n3_, n4_};
    int stride = gridDim.x * blockDim.x;
    int t0 = blockIdx.x * blockDim.x + threadIdx.x;
#pragma unroll
    for (int a = 0; a < 5; ++a) {
        const float4* src = (const float4*)srcs[a];
        bf4* dst = (bf4*)dsts[a];
        int n4 = ns[a] >> 2;
        for (int i = t0; i < n4; i += stride) {
            float4 v = src[i];
            bf4 o = {__float2bfloat16(v.x), __float2bfloat16(v.y),
                     __float2bfloat16(v.z), __float2bfloat16(v.w)};
            dst[i] = o;
        }
    }
}

// ---------------------------------------------------------------------------
// GEMM staging into XOR-16 swizzled [64][128] LDS tile (single-buffered,
// 8 K-iters at BK=128, 256 threads): inst t covers rows 4t..4t+3.
#define GEMM_STAGE(dst, src_base, row0, ldk)                                   \
    _Pragma("unroll")                                                          \
    for (int u = 0; u < 4; ++u) {                                              \
        int t = wave * 4 + u;                                                  \
        int row = t * 4 + (lane >> 4);                                         \
        int gsrc = (lane & 15) ^ (row & 15);                                   \
        async_cp16(&dst[t * 4][0], src_base + (size_t)(row0 + row) * ldk + k0 + gsrc * 8); \
    }

// ---------------------------------------------------------------------------
// Fused Q/K/V projection. A = hsb [M,K]. N-tiles: 0..15 -> Q (scaled 1/8),
// 16 -> K, 17 -> V (stored transposed). Tile 64(M)x64(N), BK=128, 256 thr.
// Wave grid 2x2. XCD-SWIZZLED 1D grid (576 blocks, bijective): XCD k owns
// m-tiles [4k,4k+4) x ALL 18 N-tiles -> A-slice + weight panel L2-resident.
__global__ void qkv_proj_kernel(const bf16* __restrict__ A,
                                const bf16* __restrict__ Wq, const bf16* __restrict__ Wk,
                                const bf16* __restrict__ Wv,
                                const float* __restrict__ bq, const float* __restrict__ bk,
                                const float* __restrict__ bv,
                                bf16* __restrict__ qo, bf16* __restrict__ ko,
                                bf16* __restrict__ vto, int M, int K) {
    __shared__ __align__(16) bf16 As[64][128]; // 16 KB
    __shared__ __align__(16) bf16 Bs[64][128]; // 16 KB

    const int lin = blockIdx.x;                 // 0..575
    const int w = (lin & 7) * 72 + (lin >> 3);  // 576/8 = 72 work items/XCD
    const int nt = w % 18;                      // N-tile (x fastest within XCD)
    const int m0 = (w / 18) * 64;               // m-tile contiguous per XCD

    const bf16* W;
    const float* bias;
    int mode, nw0;
    if (nt < 16)      { W = Wq; bias = bq; mode = 0; nw0 = nt * 64; }
    else if (nt == 16){ W = Wk; bias = bk; mode = 1; nw0 = 0; }
    else              { W = Wv; bias = bv; mode = 2; nw0 = 0; }

    const int tid = threadIdx.x;
    const int wave = tid >> 6, lane = tid & 63;
    const int l16 = lane & 15, quad = lane >> 4;
    const int wr = wave >> 1, wc = wave & 1;

    f32x4 acc[2][2];
    const f32x4 z = {0.f, 0.f, 0.f, 0.f};
#pragma unroll
    for (int mi = 0; mi < 2; ++mi)
#pragma unroll
        for (int ni = 0; ni < 2; ++ni) acc[mi][ni] = z;

    for (int k0 = 0; k0 < K; k0 += 128) {
        GEMM_STAGE(As, A, m0, K)
        GEMM_STAGE(Bs, W, nw0, K)
        __syncthreads();

        short8 af[2][4], bfr[2][4];
#pragma unroll
        for (int mi = 0; mi < 2; ++mi) {
            int R = wr * 32 + mi * 16 + l16;
#pragma unroll
            for (int kc = 0; kc < 4; ++kc)
                af[mi][kc] = ld8(&As[R][((kc * 4 + quad) ^ (R & 15)) * 8]);
        }
#pragma unroll
        for (int ni = 0; ni < 2; ++ni) {
            int r = wc * 32 + ni * 16 + l16;
#pragma unroll
            for (int kc = 0; kc < 4; ++kc)
                bfr[ni][kc] = ld8(&Bs[r][((kc * 4 + quad) ^ (r & 15)) * 8]);
        }
#pragma unroll
        for (int kc = 0; kc < 4; ++kc)
#pragma unroll
            for (int mi = 0; mi < 2; ++mi)
#pragma unroll
                for (int ni = 0; ni < 2; ++ni)
                    acc[mi][ni] = __builtin_amdgcn_mfma_f32_16x16x32_bf16(
                        af[mi][kc], bfr[ni][kc], acc[mi][ni], 0, 0, 0);
        __syncthreads();
    }

#pragma unroll
    for (int mi = 0; mi < 2; ++mi)
#pragma unroll
        for (int ni = 0; ni < 2; ++ni)
#pragma unroll
            for (int r = 0; r < 4; ++r) {
                int row = m0 + wr * 32 + mi * 16 + quad * 4 + r;
                int c = wc * 32 + ni * 16 + l16;      // 0..63 within N-tile
                float v = acc[mi][ni][r] + bias[nw0 + c];
                if (mode == 0)
                    qo[(size_t)row * 1024 + nt * 64 + c] = __float2bfloat16(v * 0.125f);
                else if (mode == 1)
                    ko[(size_t)row * 64 + c] = __float2bfloat16(v);
                else
                    vto[(size_t)c * M + row] = __float2bfloat16(v);
            }
}

// ---------------------------------------------------------------------------
// C[M,N] = A[M,K](bf16) @ W[N,K](bf16)^T + bias (fp32 out). 64x64, BK=128,
// wave grid 2x2. XCD-SWIZZLED 1D grid (bijective): XCD k owns contiguous
// m-tiles x all n-tiles -> A rows + W panel L2-resident (T1).
__global__ void gemm_bt_mfma(const bf16* __restrict__ A, const bf16* __restrict__ W,
                             const float* __restrict__ bias, float* __restrict__ C,
                             int M, int N, int K) {
    __shared__ __align__(16) bf16 As[64][128];
    __shared__ __align__(16) bf16 Bs[64][128];
    const int tid = threadIdx.x;
    const int wave = tid >> 6, lane = tid & 63;
    const int l16 = lane & 15, quad = lane >> 4;
    const int wr = wave >> 1, wc = wave & 1;

    const int ntn = N / 64;                       // n-tiles
    const int tot = (M / 64) * ntn;
    const int cpx = tot >> 3;                     // work items per XCD
    const int lin = blockIdx.x;
    const int w = (lin & 7) * cpx + (lin >> 3);
    const int n0 = (w % ntn) * 64;
    const int m0 = (w / ntn) * 64;

    f32x4 acc[2][2];
    const f32x4 z = {0.f, 0.f, 0.f, 0.f};
#pragma unroll
    for (int mi = 0; mi < 2; ++mi)
#pragma unroll
        for (int ni = 0; ni < 2; ++ni) acc[mi][ni] = z;

    for (int k0 = 0; k0 < K; k0 += 128) {
        GEMM_STAGE(As, A, m0, K)
        GEMM_STAGE(Bs, W, n0, K)
        __syncthreads();

        short8 af[2][4], bfr[2][4];
#pragma unroll
        for (int mi = 0; mi < 2; ++mi) {
            int R = wr * 32 + mi * 16 + l16;
#pragma unroll
            for (int kc = 0; kc < 4; ++kc)
                af[mi][kc] = ld8(&As[R][((kc * 4 + quad) ^ (R & 15)) * 8]);
        }
#pragma unroll
        for (int ni = 0; ni < 2; ++ni) {
            int r = wc * 32 + ni * 16 + l16;
#pragma unroll
            for (int kc = 0; kc < 4; ++kc)
                bfr[ni][kc] = ld8(&Bs[r][((kc * 4 + quad) ^ (r & 15)) * 8]);
        }
#pragma unroll
        for (int kc = 0; kc < 4; ++kc)
#pragma unroll
            for (int mi = 0; mi < 2; ++mi)
#pragma unroll
                for (int ni = 0; ni < 2; ++ni)
                    acc[mi][ni] = __builtin_amdgcn_mfma_f32_16x16x32_bf16(
                        af[mi][kc], bfr[ni][kc], acc[mi][ni], 0, 0, 0);
        __syncthreads();
    }

#pragma unroll
    for (int mi = 0; mi < 2; ++mi)
#pragma unroll
        for (int ni = 0; ni < 2; ++ni)
#pragma unroll
            for (int r = 0; r < 4; ++r) {
                int row = m0 + wr * 32 + mi * 16 + quad * 4 + r;
                int col = n0 + wc * 32 + ni * 16 + l16;
                C[(size_t)row * N + col] = acc[mi][ni][r] + bias[col];
            }
}

// ---------------------------------------------------------------------------
// Flash causal MQA phase A — R4 structure + K/V DOUBLE-BUFFER + setprio.
// In-register P via swapped QK^T: S^T = K·Q^T C-layout (q=l16, k=quad*4+r)
// IS the A-frag of the K=16 PV MFMA. Dbuf K/V (32.8 KB LDS, 4 blocks/CU):
// stage(next) issued BEFORE compute(cur); ONE barrier per iter whose vmcnt
// drain waits on loads issued a full compute phase (~800 cyc) earlier ->
// staging latency hidden (T3-minimum). setprio(1) around the MFMA/exp
// compute cluster (T5: blocks are mutually unsynchronized -> phase-diverse).
// 80 slots/head: s<32->(c0,i=s); <56->(c1,i=s-24); <72->(c2,i=s-40);
// else (c3,i=s-48). s<8 blocks single-chunk: write normalized attn directly.
__global__ void flash_mfma_kernel(const bf16* __restrict__ Q, const bf16* __restrict__ Kg,
                                  const bf16* __restrict__ VT,
                                  bf16* __restrict__ Opart, float* __restrict__ Lpart,
                                  bf16* __restrict__ attn, int S) {
    const int s = blockIdx.x;
    int i, c;
    if (s < 32)      { c = 0; i = s; }
    else if (s < 56) { c = 1; i = s - 24; }
    else if (s < 72) { c = 2; i = s - 40; }
    else             { c = 3; i = s - 48; }

    __shared__ __align__(16) bf16 Ks[2][64][64]; // 16 KB, 16B-chunk XOR-swizzled
    __shared__ __align__(16) bf16 Vt[2][64][64]; // 16 KB, 16B-chunk XOR-swizzled

    const int h = blockIdx.y;
    const int q0 = i * 64;
    const int tid = threadIdx.x;
    const int wave = tid >> 6, lane = tid & 63;
    const int l16 = lane & 15, quad = lane >> 4;
    const int lr = lane >> 3, lsw = (lane & 7) ^ (lr & 7);
    const int qrow = q0 + wave * 16;

    // Q fragment (B operand of swapped QK^T): col=q=l16, d=kc*32+quad*8
    short8 qf[2];
#pragma unroll
    for (int kc = 0; kc < 2; ++kc)
        qf[kc] = ld8(Q + (size_t)(qrow + l16) * 1024 + h * 64 + kc * 32 + quad * 8);

    f32x4 of[4];
    const f32x4 z = {0.f, 0.f, 0.f, 0.f};
#pragma unroll
    for (int dt = 0; dt < 4; ++dt) of[dt] = z;
    float lsum = 0.f;

    const int jt0 = c * 8;
    const int jt1 = min(c * 8 + 8, i + 1);
    const int nits = jt1 - jt0;

#define STAGE_KV(buf, jt_)                                                       \
    do {                                                                         \
        const int j0_ = (jt_) * 64;                                              \
        _Pragma("unroll")                                                        \
        for (int u = 0; u < 2; ++u) {                                            \
            int t = wave * 2 + u;                                                \
            async_cp16(&Ks[buf][t * 8][0],                                       \
                       Kg + (size_t)(j0_ + t * 8 + lr) * 64 + lsw * 8);          \
            async_cp16(&Vt[buf][t * 8][0],                                       \
                       VT + (size_t)(t * 8 + lr) * S + j0_ + lsw * 8);           \
        }                                                                        \
    } while (0)

    // prologue: stage first tile into buffer 0
    STAGE_KV(0, jt0);
    __syncthreads();

    for (int it = 0; it < nits; ++it) {
        const int jt = jt0 + it;
        const int j0 = jt * 64;
        const int cur = it & 1;
        if (it + 1 < nits) STAGE_KV(cur ^ 1, jt + 1); // prefetch next tile

        __builtin_amdgcn_s_setprio(1);
        // S^T = K Q^T (Q pre-scaled by 1/8). A=K-frag (row=k=nt*16+l16,
        // dk=quad*8..), B=Q-frag. C-layout: col=l16=q, row=quad*4+r=k-local.
        f32x4 sc[4];
#pragma unroll
        for (int nt = 0; nt < 4; ++nt) {
            int R = nt * 16 + l16;
            sc[nt] = __builtin_amdgcn_mfma_f32_16x16x32_bf16(
                ld8(&Ks[cur][R][(quad ^ (R & 7)) * 8]), qf[0], z, 0, 0, 0);
            sc[nt] = __builtin_amdgcn_mfma_f32_16x16x32_bf16(
                ld8(&Ks[cur][R][((4 + quad) ^ (R & 7)) * 8]), qf[1], sc[nt], 0, 0, 0);
        }
        // causal mask: k_global = j0+nt*16+quad*4+r vs q_global = qrow+l16
        if (j0 + 63 > qrow) {
#pragma unroll
            for (int nt = 0; nt < 4; ++nt)
#pragma unroll
                for (int r = 0; r < 4; ++r)
                    if (j0 + nt * 16 + quad * 4 + r > qrow + l16) sc[nt][r] = -1e30f;
        }

        // P = exp(S) in-register (fixed shift; masked -> exp(-1e30)==0).
        short4v p4[4];
#pragma unroll
        for (int nt = 0; nt < 4; ++nt)
#pragma unroll
            for (int r = 0; r < 4; ++r) {
                bf16 b = __float2bfloat16(__expf(sc[nt][r]));
                lsum += __bfloat162float(b);
                p4[nt][r] = *reinterpret_cast<short*>(&b);
            }

        // O += P V: per k-16-tile nt, A=p4[nt] (k=quad*4+j), B=V-frag
        // (col=d=l16, k=quad*4+j) read as ds_read_b64 from chunk-XOR'd Vt.
#pragma unroll
        for (int dt = 0; dt < 4; ++dt) {
            int d = dt * 16 + l16;
            int xr = d & 7;
#pragma unroll
            for (int nt = 0; nt < 4; ++nt) {
                int g = 2 * nt + (quad >> 1);           // 16B chunk of k-range
                short4v vf = ld4(&Vt[cur][d][((g ^ xr) * 8) + (quad & 1) * 4]);
                of[dt] = __builtin_amdgcn_mfma_f32_16x16x16bf16_1k(
                    p4[nt], vf, of[dt], 0, 0, 0);
            }
        }
        __builtin_amdgcn_s_setprio(0);
        // single barrier per iter: (a) readers of buf[cur] done before it is
        // restaged next iter; (b) drains vmcnt so buf[cur^1] is ready.
        __syncthreads();
    }
#undef STAGE_KV

    // L: lane holds partial sum over its (quad) k-slices for q=l16;
    // reduce across quads (lanes differing in bits 4,5).
    float Lred = lsum;
    Lred += __shfl_xor(Lred, 16);
    Lred += __shfl_xor(Lred, 32);

    if (s < 8) {
        // single-chunk q-tile: L complete -> write normalized attn directly.
        float inv[4];
#pragma unroll
        for (int r = 0; r < 4; ++r)
            inv[r] = 1.f / __shfl(Lred, quad * 4 + r);
#pragma unroll
        for (int dt = 0; dt < 4; ++dt)
#pragma unroll
            for (int r = 0; r < 4; ++r) {
                int row = q0 + wave * 16 + quad * 4 + r;
                attn[(size_t)row * 1024 + h * 64 + dt * 16 + l16] =
                    __float2bfloat16(of[dt][r] * inv[r]);
            }
        return;
    }

    // partials at slot (s, h): O as bf16 (64x64), L fp32
    bf16* Op = Opart + ((size_t)s * 16 + h) * 4096;
#pragma unroll
    for (int dt = 0; dt < 4; ++dt)
#pragma unroll
        for (int r = 0; r < 4; ++r) {
            int row = wave * 16 + quad * 4 + r;
            Op[row * 64 + dt * 16 + l16] = __float2bfloat16(of[dt][r]);
        }
    if (quad == 0) {
        float* L = Lpart + ((size_t)s * 16 + h) * 64;
        L[wave * 16 + l16] = Lred;
    }
}

// ---------------------------------------------------------------------------
// Merge 2..4 partials per (q-tile i>=8, head h): plain sums.
__global__ void flash_merge_kernel(const bf16* __restrict__ Opart,
                                   const float* __restrict__ Lpart,
                                   bf16* __restrict__ attn) {
    const int i = blockIdx.x + 8, h = blockIdx.y; // q-tiles 8..31
    const int nch = (i >> 3) + 1;                 // 2..4 chunks
    const int tid = threadIdx.x;
    const int row = tid >> 2, cg = (tid & 3) * 16;

    float L = 0.f;
    for (int cc = 0; cc < nch; ++cc) {
        int s = (cc == 0) ? i : (cc == 1) ? 24 + i : (cc == 2) ? 40 + i : 48 + i;
        L += Lpart[((size_t)s * 16 + h) * 64 + row];
    }
    float inv = 1.f / L;

    float o[16];
#pragma unroll
    for (int j = 0; j < 16; ++j) o[j] = 0.f;
    for (int cc = 0; cc < nch; ++cc) {
        int s = (cc == 0) ? i : (cc == 1) ? 24 + i : (cc == 2) ? 40 + i : 48 + i;
        const bf16* Op = Opart + ((size_t)s * 16 + h) * 4096 + row * 64 + cg;
#pragma unroll
        for (int j = 0; j < 16; ++j) o[j] += __bfloat162float(Op[j]);
    }
    bf16* dst = attn + (size_t)(i * 64 + row) * 1024 + h * 64 + cg;
#pragma unroll
    for (int j = 0; j < 16; ++j) dst[j] = __float2bfloat16(o[j] * inv);
}

// ---------------------------------------------------------------------------
extern "C" void kernel_launch(void* const* d_in, const int* in_sizes, int n_in,
                              void* d_out, int out_size, void* d_ws, size_t ws_size,
                              hipStream_t stream) {
    const int S = 2048, E = 1024, D = 64;

    const float* hs = (const float*)d_in[0];
    const float* Wq = (const float*)d_in[2];
    const float* bq = (const float*)d_in[3];
    const float* Wk = (const float*)d_in[4];
    const float* bk = (const float*)d_in[5];
    const float* Wv = (const float*)d_in[6];
    const float* bv = (const float*)d_in[7];
    const float* Wo = (const float*)d_in[8];
    const float* bo = (const float*)d_in[9];
    float* out = (float*)d_out;

    bf16* ws = (bf16*)d_ws;
    bf16* hsb = ws;                       // S*E
    bf16* wqb = hsb + (size_t)S * E;      // E*E
    bf16* wkb = wqb + (size_t)E * E;      // D*E
    bf16* wvb = wkb + (size_t)D * E;      // D*E
    bf16* wob = wvb + (size_t)D * E;      // E*E
    bf16* q = wob + (size_t)E * E;        // S*E (holds Q * 1/8)
    bf16* kbuf = q + (size_t)S * E;       // S*D
    bf16* vt = kbuf + (size_t)S * D;      // D*S (transposed)
    bf16* attn = vt + (size_t)S * D;      // S*E
    bf16* Opart = attn + (size_t)S * E;   // 1280 slots * 4096 bf16 (10.5 MB)
    float* Lpart = (float*)(Opart + (size_t)1280 * 4096); // 1280 * 64 f32

    cast_kernel<<<512, 256, 0, stream>>>(hs, hsb, S * E,
                                         Wq, wqb, E * E,
                                         Wk, wkb, D * E,
                                         Wv, wvb, D * E,
                                         Wo, wob, E * E);
    // fused Q/K/V projection (Q pre-scaled by 1/8): 576 XCD-swizzled blocks
    qkv_proj_kernel<<<dim3(18 * (S / 64)), 256, 0, stream>>>(hsb, wqb, wkb, wvb,
                                                             bq, bk, bv,
                                                             q, kbuf, vt, S, E);
    // attention: chunk=8 k-split, dbuf K/V + setprio; i<8 writes attn directly
    flash_mfma_kernel<<<dim3(80, 16), 256, 0, stream>>>(q, kbuf, vt, Opart, Lpart, attn, S);
    flash_merge_kernel<<<dim3(24, 16), 256, 0, stream>>>(Opart, Lpart, attn);
    // output projection (fp32 out): 512 XCD-swizzled blocks
    gemm_bt_mfma<<<dim3((S / 64) * (E / 64)), 256, 0, stream>>>(attn, wob, bo, out, S, E, E);
}

// Round 10
// 133.924 us; speedup vs baseline: 1.0467x; 1.0467x over previous
//
#include <hip/hip_runtime.h>
#include <hip/hip_bf16.h>

typedef __hip_bfloat16 bf16;
typedef __attribute__((ext_vector_type(8))) short short8;   // 8 bf16 = 4 VGPRs
typedef __attribute__((ext_vector_type(4))) short short4v;  // 4 bf16 = 2 VGPRs
typedef __attribute__((ext_vector_type(4))) float f32x4;    // MFMA C/D frag

__device__ __forceinline__ short8 ld8(const void* p) { return *(const short8*)p; }
__device__ __forceinline__ short4v ld4(const void* p) { return *(const short4v*)p; }

// async global->LDS, 16B per lane: LDS dest = (wave-uniform) base + lane*16
__device__ __forceinline__ void async_cp16(bf16* lds, const bf16* g) {
    __builtin_amdgcn_global_load_lds(
        (const __attribute__((address_space(1))) unsigned int*)g,
        (__attribute__((address_space(3))) unsigned int*)lds, 16, 0, 0);
}

struct bf4 { bf16 a, b, c, d; };

// ---------------------------------------------------------------------------
__global__ void cast_kernel(const float* __restrict__ s0, bf16* __restrict__ d0, int n0_,
                            const float* __restrict__ s1, bf16* __restrict__ d1, int n1_,
                            const float* __restrict__ s2, bf16* __restrict__ d2, int n2_,
                            const float* __restrict__ s3, bf16* __restrict__ d3, int n3_,
                            const float* __restrict__ s4, bf16* __restrict__ d4, int n4_) {
    const float* srcs[5] = {s0, s1, s2, s3, s4};
    bf16* dsts[5] = {d0, d1, d2, d3, d4};
    int ns[5] = {n0_, n1_, n2_, n3_, n4_};
    int stride = gridDim.x * blockDim.x;
    int t0 = blockIdx.x * blockDim.x + threadIdx.x;
#pragma unroll
    for (int a = 0; a < 5; ++a) {
        const float4* src = (const float4*)srcs[a];
        bf4* dst = (bf4*)dsts[a];
        int n4 = ns[a] >> 2;
        for (int i = t0; i < n4; i += stride) {
            float4 v = src[i];
            bf4 o = {__float2bfloat16(v.x), __float2bfloat16(v.y),
                     __float2bfloat16(v.z), __float2bfloat16(v.w)};
            dst[i] = o;
        }
    }
}

// ---------------------------------------------------------------------------
// GEMM staging into XOR-16 swizzled [64][128] LDS tile (single-buffered,
// 8 K-iters at BK=128, 256 threads): inst t covers rows 4t..4t+3.
#define GEMM_STAGE(dst, src_base, row0, ldk)                                   \
    _Pragma("unroll")                                                          \
    for (int u = 0; u < 4; ++u) {                                              \
        int t = wave * 4 + u;                                                  \
        int row = t * 4 + (lane >> 4);                                         \
        int gsrc = (lane & 15) ^ (row & 15);                                   \
        async_cp16(&dst[t * 4][0], src_base + (size_t)(row0 + row) * ldk + k0 + gsrc * 8); \
    }

// ---------------------------------------------------------------------------
// Fused Q/K/V projection. A = hsb [M,K]. N-tiles: 0..15 -> Q (scaled 1/8),
// 16 -> K, 17 -> V (stored transposed). Tile 64(M)x64(N), BK=128, 256 thr.
// Wave grid 2x2. XCD-SWIZZLED 1D grid (576 blocks, bijective): XCD k owns
// m-tiles [4k,4k+4) x ALL 18 N-tiles -> A-slice + weight panel L2-resident.
__global__ void qkv_proj_kernel(const bf16* __restrict__ A,
                                const bf16* __restrict__ Wq, const bf16* __restrict__ Wk,
                                const bf16* __restrict__ Wv,
                                const float* __restrict__ bq, const float* __restrict__ bk,
                                const float* __restrict__ bv,
                                bf16* __restrict__ qo, bf16* __restrict__ ko,
                                bf16* __restrict__ vto, int M, int K) {
    __shared__ __align__(16) bf16 As[64][128]; // 16 KB
    __shared__ __align__(16) bf16 Bs[64][128]; // 16 KB

    const int lin = blockIdx.x;                 // 0..575
    const int w = (lin & 7) * 72 + (lin >> 3);  // 576/8 = 72 work items/XCD
    const int nt = w % 18;                      // N-tile (x fastest within XCD)
    const int m0 = (w / 18) * 64;               // m-tile contiguous per XCD

    const bf16* W;
    const float* bias;
    int mode, nw0;
    if (nt < 16)      { W = Wq; bias = bq; mode = 0; nw0 = nt * 64; }
    else if (nt == 16){ W = Wk; bias = bk; mode = 1; nw0 = 0; }
    else              { W = Wv; bias = bv; mode = 2; nw0 = 0; }

    const int tid = threadIdx.x;
    const int wave = tid >> 6, lane = tid & 63;
    const int l16 = lane & 15, quad = lane >> 4;
    const int wr = wave >> 1, wc = wave & 1;

    f32x4 acc[2][2];
    const f32x4 z = {0.f, 0.f, 0.f, 0.f};
#pragma unroll
    for (int mi = 0; mi < 2; ++mi)
#pragma unroll
        for (int ni = 0; ni < 2; ++ni) acc[mi][ni] = z;

    for (int k0 = 0; k0 < K; k0 += 128) {
        GEMM_STAGE(As, A, m0, K)
        GEMM_STAGE(Bs, W, nw0, K)
        __syncthreads();

        short8 af[2][4], bfr[2][4];
#pragma unroll
        for (int mi = 0; mi < 2; ++mi) {
            int R = wr * 32 + mi * 16 + l16;
#pragma unroll
            for (int kc = 0; kc < 4; ++kc)
                af[mi][kc] = ld8(&As[R][((kc * 4 + quad) ^ (R & 15)) * 8]);
        }
#pragma unroll
        for (int ni = 0; ni < 2; ++ni) {
            int r = wc * 32 + ni * 16 + l16;
#pragma unroll
            for (int kc = 0; kc < 4; ++kc)
                bfr[ni][kc] = ld8(&Bs[r][((kc * 4 + quad) ^ (r & 15)) * 8]);
        }
#pragma unroll
        for (int kc = 0; kc < 4; ++kc)
#pragma unroll
            for (int mi = 0; mi < 2; ++mi)
#pragma unroll
                for (int ni = 0; ni < 2; ++ni)
                    acc[mi][ni] = __builtin_amdgcn_mfma_f32_16x16x32_bf16(
                        af[mi][kc], bfr[ni][kc], acc[mi][ni], 0, 0, 0);
        __syncthreads();
    }

#pragma unroll
    for (int mi = 0; mi < 2; ++mi)
#pragma unroll
        for (int ni = 0; ni < 2; ++ni)
#pragma unroll
            for (int r = 0; r < 4; ++r) {
                int row = m0 + wr * 32 + mi * 16 + quad * 4 + r;
                int c = wc * 32 + ni * 16 + l16;      // 0..63 within N-tile
                float v = acc[mi][ni][r] + bias[nw0 + c];
                if (mode == 0)
                    qo[(size_t)row * 1024 + nt * 64 + c] = __float2bfloat16(v * 0.125f);
                else if (mode == 1)
                    ko[(size_t)row * 64 + c] = __float2bfloat16(v);
                else
                    vto[(size_t)c * M + row] = __float2bfloat16(v);
            }
}

// ---------------------------------------------------------------------------
// C[M,N] = A[M,K](bf16) @ W[N,K](bf16)^T + bias (fp32 out). 64x64, BK=128,
// wave grid 2x2. XCD-SWIZZLED 1D grid (bijective): XCD k owns contiguous
// m-tiles x all n-tiles -> A rows + W panel L2-resident (T1).
__global__ void gemm_bt_mfma(const bf16* __restrict__ A, const bf16* __restrict__ W,
                             const float* __restrict__ bias, float* __restrict__ C,
                             int M, int N, int K) {
    __shared__ __align__(16) bf16 As[64][128];
    __shared__ __align__(16) bf16 Bs[64][128];
    const int tid = threadIdx.x;
    const int wave = tid >> 6, lane = tid & 63;
    const int l16 = lane & 15, quad = lane >> 4;
    const int wr = wave >> 1, wc = wave & 1;

    const int ntn = N / 64;                       // n-tiles
    const int tot = (M / 64) * ntn;
    const int cpx = tot >> 3;                     // work items per XCD
    const int lin = blockIdx.x;
    const int w = (lin & 7) * cpx + (lin >> 3);
    const int n0 = (w % ntn) * 64;
    const int m0 = (w / ntn) * 64;

    f32x4 acc[2][2];
    const f32x4 z = {0.f, 0.f, 0.f, 0.f};
#pragma unroll
    for (int mi = 0; mi < 2; ++mi)
#pragma unroll
        for (int ni = 0; ni < 2; ++ni) acc[mi][ni] = z;

    for (int k0 = 0; k0 < K; k0 += 128) {
        GEMM_STAGE(As, A, m0, K)
        GEMM_STAGE(Bs, W, n0, K)
        __syncthreads();

        short8 af[2][4], bfr[2][4];
#pragma unroll
        for (int mi = 0; mi < 2; ++mi) {
            int R = wr * 32 + mi * 16 + l16;
#pragma unroll
            for (int kc = 0; kc < 4; ++kc)
                af[mi][kc] = ld8(&As[R][((kc * 4 + quad) ^ (R & 15)) * 8]);
        }
#pragma unroll
        for (int ni = 0; ni < 2; ++ni) {
            int r = wc * 32 + ni * 16 + l16;
#pragma unroll
            for (int kc = 0; kc < 4; ++kc)
                bfr[ni][kc] = ld8(&Bs[r][((kc * 4 + quad) ^ (r & 15)) * 8]);
        }
#pragma unroll
        for (int kc = 0; kc < 4; ++kc)
#pragma unroll
            for (int mi = 0; mi < 2; ++mi)
#pragma unroll
                for (int ni = 0; ni < 2; ++ni)
                    acc[mi][ni] = __builtin_amdgcn_mfma_f32_16x16x32_bf16(
                        af[mi][kc], bfr[ni][kc], acc[mi][ni], 0, 0, 0);
        __syncthreads();
    }

#pragma unroll
    for (int mi = 0; mi < 2; ++mi)
#pragma unroll
        for (int ni = 0; ni < 2; ++ni)
#pragma unroll
            for (int r = 0; r < 4; ++r) {
                int row = m0 + wr * 32 + mi * 16 + quad * 4 + r;
                int col = n0 + wc * 32 + ni * 16 + l16;
                C[(size_t)row * N + col] = acc[mi][ni][r] + bias[col];
            }
}

// ---------------------------------------------------------------------------
// Flash causal MQA phase A — R4 structure (proven best), unchanged.
// In-register P via swapped QK^T: S^T = K·Q^T C-layout (q=l16, k=quad*4+r)
// IS the A-frag of the K=16 PV MFMA. Single-buffered K/V (16.4 KB LDS,
// 5 blocks/CU — TLP beats dbuf here, measured 3x: R1/R6/R9).
// 80 slots/head: s<32->(c0,i=s); <56->(c1,i=s-24); <72->(c2,i=s-40);
// else (c3,i=s-48). s<8 blocks single-chunk: write normalized attn directly.
__global__ void flash_mfma_kernel(const bf16* __restrict__ Q, const bf16* __restrict__ Kg,
                                  const bf16* __restrict__ VT,
                                  bf16* __restrict__ Opart, float* __restrict__ Lpart,
                                  bf16* __restrict__ attn, int S) {
    const int s = blockIdx.x;
    int i, c;
    if (s < 32)      { c = 0; i = s; }
    else if (s < 56) { c = 1; i = s - 24; }
    else if (s < 72) { c = 2; i = s - 40; }
    else             { c = 3; i = s - 48; }

    __shared__ __align__(16) bf16 Ks[64][64]; // 8 KB, 16B-chunk XOR-swizzled
    __shared__ __align__(16) bf16 Vt[64][64]; // 8 KB, 16B-chunk XOR-swizzled

    const int h = blockIdx.y;
    const int q0 = i * 64;
    const int tid = threadIdx.x;
    const int wave = tid >> 6, lane = tid & 63;
    const int l16 = lane & 15, quad = lane >> 4;
    const int lr = lane >> 3, lsw = (lane & 7) ^ (lr & 7);
    const int qrow = q0 + wave * 16;

    // Q fragment (B operand of swapped QK^T): col=q=l16, d=kc*32+quad*8
    short8 qf[2];
#pragma unroll
    for (int kc = 0; kc < 2; ++kc)
        qf[kc] = ld8(Q + (size_t)(qrow + l16) * 1024 + h * 64 + kc * 32 + quad * 8);

    f32x4 of[4];
    const f32x4 z = {0.f, 0.f, 0.f, 0.f};
#pragma unroll
    for (int dt = 0; dt < 4; ++dt) of[dt] = z;
    float lsum = 0.f;

    const int jt0 = c * 8;
    const int jt1 = min(c * 8 + 8, i + 1);

    for (int jt = jt0; jt < jt1; ++jt) {
        const int j0 = jt * 64;
        // stage K/V tile (prior iter's readers finished at loop-end barrier)
#pragma unroll
        for (int u = 0; u < 2; ++u) {
            int t = wave * 2 + u;
            async_cp16(&Ks[t * 8][0], Kg + (size_t)(j0 + t * 8 + lr) * 64 + lsw * 8);
            async_cp16(&Vt[t * 8][0], VT + (size_t)(t * 8 + lr) * S + j0 + lsw * 8);
        }
        __syncthreads(); // staged data visible (drains vmcnt)

        // S^T = K Q^T (Q pre-scaled by 1/8). A=K-frag (row=k=nt*16+l16,
        // dk=quad*8..), B=Q-frag. C-layout: col=l16=q, row=quad*4+r=k-local.
        f32x4 sc[4];
#pragma unroll
        for (int nt = 0; nt < 4; ++nt) {
            int R = nt * 16 + l16;
            sc[nt] = __builtin_amdgcn_mfma_f32_16x16x32_bf16(
                ld8(&Ks[R][(quad ^ (R & 7)) * 8]), qf[0], z, 0, 0, 0);
            sc[nt] = __builtin_amdgcn_mfma_f32_16x16x32_bf16(
                ld8(&Ks[R][((4 + quad) ^ (R & 7)) * 8]), qf[1], sc[nt], 0, 0, 0);
        }
        // causal mask: k_global = j0+nt*16+quad*4+r vs q_global = qrow+l16
        if (j0 + 63 > qrow) {
#pragma unroll
            for (int nt = 0; nt < 4; ++nt)
#pragma unroll
                for (int r = 0; r < 4; ++r)
                    if (j0 + nt * 16 + quad * 4 + r > qrow + l16) sc[nt][r] = -1e30f;
        }

        // P = exp(S) in-register (fixed shift; masked -> exp(-1e30)==0).
        short4v p4[4];
#pragma unroll
        for (int nt = 0; nt < 4; ++nt)
#pragma unroll
            for (int r = 0; r < 4; ++r) {
                bf16 b = __float2bfloat16(__expf(sc[nt][r]));
                lsum += __bfloat162float(b);
                p4[nt][r] = *reinterpret_cast<short*>(&b);
            }

        // O += P V: per k-16-tile nt, A=p4[nt] (k=quad*4+j), B=V-frag
        // (col=d=l16, k=quad*4+j) read as ds_read_b64 from chunk-XOR'd Vt.
#pragma unroll
        for (int dt = 0; dt < 4; ++dt) {
            int d = dt * 16 + l16;
            int xr = d & 7;
#pragma unroll
            for (int nt = 0; nt < 4; ++nt) {
                int g = 2 * nt + (quad >> 1);           // 16B chunk of k-range
                short4v vf = ld4(&Vt[d][((g ^ xr) * 8) + (quad & 1) * 4]);
                of[dt] = __builtin_amdgcn_mfma_f32_16x16x16bf16_1k(
                    p4[nt], vf, of[dt], 0, 0, 0);
            }
        }
        __syncthreads(); // all readers done before next iter overwrites Ks/Vt
    }

    // L: lane holds partial sum over its (quad) k-slices for q=l16;
    // reduce across quads (lanes differing in bits 4,5).
    float Lred = lsum;
    Lred += __shfl_xor(Lred, 16);
    Lred += __shfl_xor(Lred, 32);

    if (s < 8) {
        // single-chunk q-tile: L complete -> write normalized attn directly.
        float inv[4];
#pragma unroll
        for (int r = 0; r < 4; ++r)
            inv[r] = 1.f / __shfl(Lred, quad * 4 + r);
#pragma unroll
        for (int dt = 0; dt < 4; ++dt)
#pragma unroll
            for (int r = 0; r < 4; ++r) {
                int row = q0 + wave * 16 + quad * 4 + r;
                attn[(size_t)row * 1024 + h * 64 + dt * 16 + l16] =
                    __float2bfloat16(of[dt][r] * inv[r]);
            }
        return;
    }

    // partials at slot (s, h): O as bf16 (64x64), L fp32
    bf16* Op = Opart + ((size_t)s * 16 + h) * 4096;
#pragma unroll
    for (int dt = 0; dt < 4; ++dt)
#pragma unroll
        for (int r = 0; r < 4; ++r) {
            int row = wave * 16 + quad * 4 + r;
            Op[row * 64 + dt * 16 + l16] = __float2bfloat16(of[dt][r]);
        }
    if (quad == 0) {
        float* L = Lpart + ((size_t)s * 16 + h) * 64;
        L[wave * 16 + l16] = Lred;
    }
}

// ---------------------------------------------------------------------------
// Merge 2..4 partials per (q-tile i>=8, head h): plain sums.
__global__ void flash_merge_kernel(const bf16* __restrict__ Opart,
                                   const float* __restrict__ Lpart,
                                   bf16* __restrict__ attn) {
    const int i = blockIdx.x + 8, h = blockIdx.y; // q-tiles 8..31
    const int nch = (i >> 3) + 1;                 // 2..4 chunks
    const int tid = threadIdx.x;
    const int row = tid >> 2, cg = (tid & 3) * 16;

    float L = 0.f;
    for (int cc = 0; cc < nch; ++cc) {
        int s = (cc == 0) ? i : (cc == 1) ? 24 + i : (cc == 2) ? 40 + i : 48 + i;
        L += Lpart[((size_t)s * 16 + h) * 64 + row];
    }
    float inv = 1.f / L;

    float o[16];
#pragma unroll
    for (int j = 0; j < 16; ++j) o[j] = 0.f;
    for (int cc = 0; cc < nch; ++cc) {
        int s = (cc == 0) ? i : (cc == 1) ? 24 + i : (cc == 2) ? 40 + i : 48 + i;
        const bf16* Op = Opart + ((size_t)s * 16 + h) * 4096 + row * 64 + cg;
#pragma unroll
        for (int j = 0; j < 16; ++j) o[j] += __bfloat162float(Op[j]);
    }
    bf16* dst = attn + (size_t)(i * 64 + row) * 1024 + h * 64 + cg;
#pragma unroll
    for (int j = 0; j < 16; ++j) dst[j] = __float2bfloat16(o[j] * inv);
}

// ---------------------------------------------------------------------------
extern "C" void kernel_launch(void* const* d_in, const int* in_sizes, int n_in,
                              void* d_out, int out_size, void* d_ws, size_t ws_size,
                              hipStream_t stream) {
    const int S = 2048, E = 1024, D = 64;

    const float* hs = (const float*)d_in[0];
    const float* Wq = (const float*)d_in[2];
    const float* bq = (const float*)d_in[3];
    const float* Wk = (const float*)d_in[4];
    const float* bk = (const float*)d_in[5];
    const float* Wv = (const float*)d_in[6];
    const float* bv = (const float*)d_in[7];
    const float* Wo = (const float*)d_in[8];
    const float* bo = (const float*)d_in[9];
    float* out = (float*)d_out;

    bf16* ws = (bf16*)d_ws;
    bf16* hsb = ws;                       // S*E
    bf16* wqb = hsb + (size_t)S * E;      // E*E
    bf16* wkb = wqb + (size_t)E * E;      // D*E
    bf16* wvb = wkb + (size_t)D * E;      // D*E
    bf16* wob = wvb + (size_t)D * E;      // E*E
    bf16* q = wob + (size_t)E * E;        // S*E (holds Q * 1/8)
    bf16* kbuf = q + (size_t)S * E;       // S*D
    bf16* vt = kbuf + (size_t)S * D;      // D*S (transposed)
    bf16* attn = vt + (size_t)S * D;      // S*E
    bf16* Opart = attn + (size_t)S * E;   // 1280 slots * 4096 bf16 (10.5 MB)
    float* Lpart = (float*)(Opart + (size_t)1280 * 4096); // 1280 * 64 f32

    cast_kernel<<<512, 256, 0, stream>>>(hs, hsb, S * E,
                                         Wq, wqb, E * E,
                                         Wk, wkb, D * E,
                                         Wv, wvb, D * E,
                                         Wo, wob, E * E);
    // fused Q/K/V projection (Q pre-scaled by 1/8): 576 XCD-swizzled blocks
    qkv_proj_kernel<<<dim3(18 * (S / 64)), 256, 0, stream>>>(hsb, wqb, wkb, wvb,
                                                             bq, bk, bv,
                                                             q, kbuf, vt, S, E);
    // attention: chunk=8 k-split, in-register P; i<8 writes attn directly
    flash_mfma_kernel<<<dim3(80, 16), 256, 0, stream>>>(q, kbuf, vt, Opart, Lpart, attn, S);
    flash_merge_kernel<<<dim3(24, 16), 256, 0, stream>>>(Opart, Lpart, attn);
    // output projection (fp32 out): 512 XCD-swizzled blocks
    gemm_bt_mfma<<<dim3((S / 64) * (E / 64)), 256, 0, stream>>>(attn, wob, bo, out, S, E, E);
}